// Round 8
// baseline (30300.540 us; speedup 1.0000x reference)
//
#include <hip/hip_runtime.h>
#include <cstdint>

#define B_SZ 64
#define T_SZ 2048
#define F_SZ 256
#define H_SZ 512

typedef _Float16 f16x8 __attribute__((ext_vector_type(8)));
typedef float f32x4 __attribute__((ext_vector_type(4)));

#if defined(__has_builtin)
#if __has_builtin(__builtin_amdgcn_fdot2)
#define HAVE_FDOT2 1
#endif
#endif
#ifndef HAVE_FDOT2
#define HAVE_FDOT2 0
#endif

typedef _Float16 half2v __attribute__((ext_vector_type(2)));
union H2U { uint32_t u; half2v h; _Float16 e[2]; };

__device__ __forceinline__ float fdot2f(uint32_t a, uint32_t b, float c) {
  H2U ua, ub; ua.u = a; ub.u = b;
#if HAVE_FDOT2
  return __builtin_amdgcn_fdot2(ua.h, ub.h, c, false);
#else
  return c + (float)ua.e[0] * (float)ub.e[0] + (float)ua.e[1] * (float)ub.e[1];
#endif
}

__device__ __forceinline__ uint32_t pack2h(float x, float y) {
  H2U v; v.e[0] = (_Float16)x; v.e[1] = (_Float16)y; return v.u;
}

__device__ __forceinline__ float fast_tanh(float x) {
  float xc = fminf(9.0f, fmaxf(-9.0f, x));
  float e = __expf(2.0f * xc);
  return (e - 1.0f) / (e + 1.0f);
}

__device__ __forceinline__ f16x8 pack8(const float* p) {
  float4 v0 = *(const float4*)p;
  float4 v1 = *(const float4*)(p + 4);
  f16x8 a;
  a[0] = (_Float16)v0.x; a[1] = (_Float16)v0.y;
  a[2] = (_Float16)v0.z; a[3] = (_Float16)v0.w;
  a[4] = (_Float16)v1.x; a[5] = (_Float16)v1.y;
  a[6] = (_Float16)v1.z; a[7] = (_Float16)v1.w;
  return a;
}

// ---------------------------------------------------------------------------
// Kernel 0: zero the sync area in d_ws (flags + h-exchange buffers).
// Runs at the start of every launch -> graph-replay safe.
//   d_ws[0      .. 8191 ]: uint flags[128][16]  (64B-padded, one per WG)
//   d_ws[8192   .. +128K]: _Float16 hx[128][2][256] (double-buffered h halves)
// ---------------------------------------------------------------------------
__global__ __launch_bounds__(512) void zero_kernel(uint32_t* __restrict__ ws) {
  int idx = blockIdx.x * 512 + threadIdx.x;
  if (idx < 2048 + 32768) ws[idx] = 0;
}

// ---------------------------------------------------------------------------
// Kernel 1: xp[m,n] = q·W_ih^T + b_ih + b_hh   (unchanged — not bottleneck)
// ---------------------------------------------------------------------------
__global__ __launch_bounds__(256) void proj_kernel(
    const float* __restrict__ q, const float* __restrict__ w_ih,
    const float* __restrict__ b_ih, const float* __restrict__ b_hh,
    float* __restrict__ xp) {
  __shared__ uint32_t lds_a[16][128 + 4];
  __shared__ uint32_t lds_b[16][128 + 4];
  const int tid = threadIdx.x;
  const int nt = blockIdx.x & 3;
  const int mt = blockIdx.x >> 2;
  const int m0 = mt * 128, n0 = nt * 128;
  const int tx = tid & 15, ty = tid >> 4;
  const int sr = tid >> 3, sc4 = tid & 7;

  float bias[8];
#pragma unroll
  for (int j = 0; j < 8; ++j) {
    int n = n0 + tx * 8 + j;
    bias[j] = b_ih[n] + b_hh[n];
  }
  float acc[8][8];
#pragma unroll
  for (int i = 0; i < 8; ++i)
#pragma unroll
    for (int j = 0; j < 8; ++j) acc[i][j] = 0.f;

  for (int k0 = 0; k0 < F_SZ; k0 += 32) {
#pragma unroll
    for (int i = 0; i < 4; ++i) {
      int r = sr + 32 * i;
      float4 v = *(const float4*)(q + (size_t)(m0 + r) * F_SZ + k0 + sc4 * 4);
      lds_a[sc4 * 2 + 0][r] = pack2h(v.x, v.y);
      lds_a[sc4 * 2 + 1][r] = pack2h(v.z, v.w);
      float4 w = *(const float4*)(w_ih + (size_t)(n0 + r) * F_SZ + k0 + sc4 * 4);
      lds_b[sc4 * 2 + 0][r] = pack2h(w.x, w.y);
      lds_b[sc4 * 2 + 1][r] = pack2h(w.z, w.w);
    }
    __syncthreads();
#pragma unroll
    for (int kp = 0; kp < 16; ++kp) {
      uint32_t a8[8], b8[8];
#pragma unroll
      for (int i = 0; i < 8; ++i) a8[i] = lds_a[kp][ty * 8 + i];
#pragma unroll
      for (int j = 0; j < 8; ++j) b8[j] = lds_b[kp][tx * 8 + j];
#pragma unroll
      for (int i = 0; i < 8; ++i)
#pragma unroll
        for (int j = 0; j < 8; ++j)
          acc[i][j] = fdot2f(a8[i], b8[j], acc[i][j]);
    }
    __syncthreads();
  }
#pragma unroll
  for (int i = 0; i < 8; ++i) {
    size_t row = (size_t)(m0 + ty * 8 + i);
    float4 o0, o1;
    o0.x = acc[i][0] + bias[0]; o0.y = acc[i][1] + bias[1];
    o0.z = acc[i][2] + bias[2]; o0.w = acc[i][3] + bias[3];
    o1.x = acc[i][4] + bias[4]; o1.y = acc[i][5] + bias[5];
    o1.z = acc[i][6] + bias[6]; o1.w = acc[i][7] + bias[7];
    *(float4*)(xp + row * H_SZ + n0 + tx * 8) = o0;
    *(float4*)(xp + row * H_SZ + n0 + tx * 8 + 4) = o1;
  }
}

// ---------------------------------------------------------------------------
// Kernel 2: recurrence, W split across TWO CUs per batch (128 WGs total).
// wg = half*64 + batch; partner = wg ^ 64 (same XCD under %8 round-robin).
// Each WG owns rows [256*half, +256): per wave 32 rows = 2 row-tiles x 16
// k-tiles of mfma_f32_16x16x32_f16 A-frags = 128 regs/thread, ALL in AGPR
// (r6-proven budget) -> zero W traffic on LDS/L2.
// Per step: own-half h from LDS (8 broadcast b128), partner half from L2
// (8 b128, double-buffered hx in d_ws), 32 MFMAs in 4 chains (own kts
// first to cover partner-load latency), uniform select epilogue, one
// vmcnt+lgkm drain + s_barrier, then tid0 posts flag=t+1 (release, agent).
// af is stored own-kts-first so all fragment indices are compile-time.
// A-frag af[tile][j]: j<8 -> global kt 8*half+j, j>=8 -> kt 8*(1-half)+j-8.
// C/D layout (HW-verified): col=lane&15, row=(lane>>4)*4+reg.
// ---------------------------------------------------------------------------
__global__ __attribute__((amdgpu_flat_work_group_size(512, 512),
                          amdgpu_waves_per_eu(2, 2)))
void rnn_kernel(const float* __restrict__ w_hh, float* __restrict__ out,
                uint32_t* __restrict__ flags, _Float16* __restrict__ hx) {
  __shared__ _Float16 lds_h[2][256];

  const int wg = blockIdx.x;
  const int batch = wg & 63;
  const int half = wg >> 6;
  const int partner = wg ^ 64;
  const int tid = threadIdx.x;
  const int w = tid >> 6;
  const int lane = tid & 63;
  const int m = lane & 15;   // A row within tile / C col
  const int g = lane >> 4;   // k-group / C row-group

  // --- AGPR A-fragments, own-kts-first ordering ---
  f16x8 af[2][16];
#pragma unroll
  for (int tile = 0; tile < 2; ++tile) {
    const float* rowp =
        w_hh + (size_t)(256 * half + 32 * w + 16 * tile + m) * H_SZ;
#pragma unroll
    for (int j = 0; j < 16; ++j) {
      int ktg = (j < 8) ? (8 * half + j) : (8 * (1 - half) + (j - 8));
      af[tile][j] = pack8(rowp + ktg * 32 + g * 8);
    }
  }
  if (tid < 256) {
    lds_h[0][tid] = (_Float16)0.f;
    lds_h[1][tid] = (_Float16)0.f;
  }
  __syncthreads();

  // lane duty: row = 256*half + 32w + 16*tile + 4g + reg; m bit2 splits
  // out-writer (0) vs global-h-writer (1); both compute the same row value.
  const int reg = m & 3;
  const int tilesel = (m >> 3) & 1;
  const int row_loc = 32 * w + 16 * tilesel + 4 * g + reg;  // 0..255
  const int row = 256 * half + row_loc;
  const bool out_writer = (m & 4) == 0;
  const bool t1 = tilesel != 0, bb2 = (m & 2) != 0, bb1 = (m & 1) != 0;

  uint32_t* pflag = flags + partner * 16;
  uint32_t* myflag = flags + wg * 16;
  const _Float16* hxp = hx + (size_t)partner * 512;  // partner's dbuf
  _Float16* hxm = hx + (size_t)wg * 512;             // my dbuf

  float* outb = out + (size_t)batch * T_SZ * H_SZ;
  float xc = outb[row];  // xp for t=0
  float hlast = 0.f;

#pragma unroll 1
  for (int t = 0; t < T_SZ; ++t) {
    const int par = t & 1;
    // prefetch next xp
    int tn = (t + 1 < T_SZ) ? t + 1 : t;
    float xn = outb[(size_t)tn * H_SZ + row];

    // own-half B-frags from LDS (global kt = 8*half + j)
    f16x8 ob[8];
#pragma unroll
    for (int j = 0; j < 8; ++j)
      ob[j] = *(const f16x8*)(&lds_h[par][j * 32 + g * 8]);

    // own-half MFMAs (4 chains), covers the partner exchange latency
    f32x4 c0a = {0.f, 0.f, 0.f, 0.f}, c0b = c0a, c1a = c0a, c1b = c0a;
#pragma unroll
    for (int j = 0; j < 8; j += 2) {
      c0a = __builtin_amdgcn_mfma_f32_16x16x32_f16(af[0][j], ob[j], c0a, 0, 0, 0);
      c1a = __builtin_amdgcn_mfma_f32_16x16x32_f16(af[1][j], ob[j], c1a, 0, 0, 0);
      c0b = __builtin_amdgcn_mfma_f32_16x16x32_f16(af[0][j + 1], ob[j + 1], c0b, 0, 0, 0);
      c1b = __builtin_amdgcn_mfma_f32_16x16x32_f16(af[1][j + 1], ob[j + 1], c1b, 0, 0, 0);
    }

    // wait for partner's h_t (flag >= t; t=0 passes on zeroed flags)
    while (__hip_atomic_load(pflag, __ATOMIC_ACQUIRE,
                             __HIP_MEMORY_SCOPE_AGENT) < (uint32_t)t) {
    }
    // partner-half B-frags from L2 (partner-local k offset = j*32 + g*8)
    f16x8 pb[8];
#pragma unroll
    for (int j = 0; j < 8; ++j)
      pb[j] = *(const f16x8*)(hxp + par * 256 + j * 32 + g * 8);
#pragma unroll
    for (int j = 0; j < 8; j += 2) {
      c0a = __builtin_amdgcn_mfma_f32_16x16x32_f16(af[0][8 + j], pb[j], c0a, 0, 0, 0);
      c1a = __builtin_amdgcn_mfma_f32_16x16x32_f16(af[1][8 + j], pb[j], c1a, 0, 0, 0);
      c0b = __builtin_amdgcn_mfma_f32_16x16x32_f16(af[0][8 + j + 1], pb[j + 1], c0b, 0, 0, 0);
      c1b = __builtin_amdgcn_mfma_f32_16x16x32_f16(af[1][8 + j + 1], pb[j + 1], c1b, 0, 0, 0);
    }
    f32x4 d0 = c0a + c0b, d1 = c1a + c1b;

    // static select: tile bit (m&8), reg bits (m&2, m&1)
    float p0 = t1 ? d1[0] : d0[0];
    float p1 = t1 ? d1[1] : d0[1];
    float p2 = t1 ? d1[2] : d0[2];
    float p3 = t1 ? d1[3] : d0[3];
    float q01 = bb1 ? p1 : p0;
    float q23 = bb1 ? p3 : p2;
    float v = bb2 ? q23 : q01;

    float hnew = fast_tanh(xc + v);
    if (out_writer) {
      outb[(size_t)t * H_SZ + row] = hnew;              // h_t overwrites xp
      lds_h[par ^ 1][row_loc] = (_Float16)hnew;         // own half, next step
    } else {
      hxm[(par ^ 1) * 256 + row_loc] = (_Float16)hnew;  // for partner
    }
    hlast = hnew;
    xc = xn;

    // drain everything (global h stores must be in L2 before release),
    // then intra-WG barrier, then publish flag.
    asm volatile("s_waitcnt vmcnt(0) lgkmcnt(0)\n\ts_barrier" ::: "memory");
    if (tid == 0)
      __hip_atomic_store(myflag, (uint32_t)(t + 1), __ATOMIC_RELEASE,
                         __HIP_MEMORY_SCOPE_AGENT);
  }

  // hidden = h_{T-1}: each WG writes its own 256 rows
  if (out_writer)
    out[(size_t)B_SZ * T_SZ * H_SZ + (size_t)batch * H_SZ + row] = hlast;
}

extern "C" void kernel_launch(void* const* d_in, const int* in_sizes, int n_in,
                              void* d_out, int out_size, void* d_ws,
                              size_t ws_size, hipStream_t stream) {
  (void)in_sizes; (void)n_in; (void)out_size; (void)ws_size;
  const float* q    = (const float*)d_in[0];
  const float* w_ih = (const float*)d_in[1];
  const float* w_hh = (const float*)d_in[2];
  const float* b_ih = (const float*)d_in[3];
  const float* b_hh = (const float*)d_in[4];
  float* out = (float*)d_out;
  uint32_t* flags = (uint32_t*)d_ws;                       // 8 KB
  _Float16* hx = (_Float16*)((char*)d_ws + 8192);          // 128 KB

  zero_kernel<<<dim3(68), dim3(512), 0, stream>>>((uint32_t*)d_ws);

  proj_kernel<<<dim3((B_SZ * T_SZ / 128) * (H_SZ / 128)), dim3(256), 0,
                stream>>>(q, w_ih, b_ih, b_hh, out);

  rnn_kernel<<<dim3(128), dim3(512), 0, stream>>>(w_hh, out, flags, hx);
}

// Round 9
// 3415.615 us; speedup vs baseline: 8.8712x; 8.8712x over previous
//
#include <hip/hip_runtime.h>
#include <cstdint>

#define B_SZ 64
#define T_SZ 2048
#define F_SZ 256
#define H_SZ 512

typedef _Float16 f16x8 __attribute__((ext_vector_type(8)));
typedef float f32x4 __attribute__((ext_vector_type(4)));

#if defined(__has_builtin)
#if __has_builtin(__builtin_amdgcn_fdot2)
#define HAVE_FDOT2 1
#endif
#endif
#ifndef HAVE_FDOT2
#define HAVE_FDOT2 0
#endif

typedef _Float16 half2v __attribute__((ext_vector_type(2)));
union H2U { uint32_t u; half2v h; _Float16 e[2]; };

__device__ __forceinline__ float fdot2f(uint32_t a, uint32_t b, float c) {
  H2U ua, ub; ua.u = a; ub.u = b;
#if HAVE_FDOT2
  return __builtin_amdgcn_fdot2(ua.h, ub.h, c, false);
#else
  return c + (float)ua.e[0] * (float)ub.e[0] + (float)ua.e[1] * (float)ub.e[1];
#endif
}

__device__ __forceinline__ uint32_t pack2h(float x, float y) {
  H2U v; v.e[0] = (_Float16)x; v.e[1] = (_Float16)y; return v.u;
}

__device__ __forceinline__ float fast_tanh(float x) {
  float xc = fminf(9.0f, fmaxf(-9.0f, x));
  float e = __expf(2.0f * xc);
  return (e - 1.0f) / (e + 1.0f);
}

__device__ __forceinline__ f16x8 pack8(const float* p) {
  float4 v0 = *(const float4*)p;
  float4 v1 = *(const float4*)(p + 4);
  f16x8 a;
  a[0] = (_Float16)v0.x; a[1] = (_Float16)v0.y;
  a[2] = (_Float16)v0.z; a[3] = (_Float16)v0.w;
  a[4] = (_Float16)v1.x; a[5] = (_Float16)v1.y;
  a[6] = (_Float16)v1.z; a[7] = (_Float16)v1.w;
  return a;
}

// Raw per-step barrier: drain LDS ops only (h-exchange visibility). Global
// xp-loads / h-stores / streamed-W loads float across it; the "memory"
// clobber keeps pre-barrier-issued loads before it and post-barrier uses
// after it (compiler-inserted counted waits at the uses).
__device__ __forceinline__ void step_barrier() {
  asm volatile("s_waitcnt lgkmcnt(0)\n\ts_barrier" ::: "memory");
}

// ---------------------------------------------------------------------------
// Kernel 0: pre-pack the streamed quarter of W_hh (rows 64w+48..63 per wave)
// into fp16 MFMA A-fragments, fragment-linear in d_ws:
//   wsf[(w*16 + kt)*64 + lane] = frag(row 64*w+48+(lane&15), k=kt*32+(lane>>4)*8)
// 8192 fragments x 16 B = 128 KB (L2-resident during the recurrence).
// ---------------------------------------------------------------------------
__global__ __launch_bounds__(512) void prep_kernel(
    const float* __restrict__ w_hh, uint4* __restrict__ wsf) {
  int idx = blockIdx.x * 512 + threadIdx.x;   // 0..8191
  int lane = idx & 63;
  int kt = (idx >> 6) & 15;
  int w = idx >> 10;
  int m = lane & 15, g = lane >> 4;
  const float* p = w_hh + (size_t)(64 * w + 48 + m) * H_SZ + kt * 32 + g * 8;
  f16x8 a = pack8(p);
  wsf[idx] = __builtin_bit_cast(uint4, a);
}

// ---------------------------------------------------------------------------
// Kernel 1: xp[m,n] = q·W_ih^T + b_ih + b_hh   (unchanged — not bottleneck)
// ---------------------------------------------------------------------------
__global__ __launch_bounds__(256) void proj_kernel(
    const float* __restrict__ q, const float* __restrict__ w_ih,
    const float* __restrict__ b_ih, const float* __restrict__ b_hh,
    float* __restrict__ xp) {
  __shared__ uint32_t lds_a[16][128 + 4];
  __shared__ uint32_t lds_b[16][128 + 4];
  const int tid = threadIdx.x;
  const int nt = blockIdx.x & 3;
  const int mt = blockIdx.x >> 2;
  const int m0 = mt * 128, n0 = nt * 128;
  const int tx = tid & 15, ty = tid >> 4;
  const int sr = tid >> 3, sc4 = tid & 7;

  float bias[8];
#pragma unroll
  for (int j = 0; j < 8; ++j) {
    int n = n0 + tx * 8 + j;
    bias[j] = b_ih[n] + b_hh[n];
  }
  float acc[8][8];
#pragma unroll
  for (int i = 0; i < 8; ++i)
#pragma unroll
    for (int j = 0; j < 8; ++j) acc[i][j] = 0.f;

  for (int k0 = 0; k0 < F_SZ; k0 += 32) {
#pragma unroll
    for (int i = 0; i < 4; ++i) {
      int r = sr + 32 * i;
      float4 v = *(const float4*)(q + (size_t)(m0 + r) * F_SZ + k0 + sc4 * 4);
      lds_a[sc4 * 2 + 0][r] = pack2h(v.x, v.y);
      lds_a[sc4 * 2 + 1][r] = pack2h(v.z, v.w);
      float4 w = *(const float4*)(w_ih + (size_t)(n0 + r) * F_SZ + k0 + sc4 * 4);
      lds_b[sc4 * 2 + 0][r] = pack2h(w.x, w.y);
      lds_b[sc4 * 2 + 1][r] = pack2h(w.z, w.w);
    }
    __syncthreads();
#pragma unroll
    for (int kp = 0; kp < 16; ++kp) {
      uint32_t a8[8], b8[8];
#pragma unroll
      for (int i = 0; i < 8; ++i) a8[i] = lds_a[kp][ty * 8 + i];
#pragma unroll
      for (int j = 0; j < 8; ++j) b8[j] = lds_b[kp][tx * 8 + j];
#pragma unroll
      for (int i = 0; i < 8; ++i)
#pragma unroll
        for (int j = 0; j < 8; ++j)
          acc[i][j] = fdot2f(a8[i], b8[j], acc[i][j]);
    }
    __syncthreads();
  }
#pragma unroll
  for (int i = 0; i < 8; ++i) {
    size_t row = (size_t)(m0 + ty * 8 + i);
    float4 o0, o1;
    o0.x = acc[i][0] + bias[0]; o0.y = acc[i][1] + bias[1];
    o0.z = acc[i][2] + bias[2]; o0.w = acc[i][3] + bias[3];
    o1.x = acc[i][4] + bias[4]; o1.y = acc[i][5] + bias[5];
    o1.z = acc[i][6] + bias[6]; o1.w = acc[i][7] + bias[7];
    *(float4*)(xp + row * H_SZ + n0 + tx * 8) = o0;
    *(float4*)(xp + row * H_SZ + n0 + tx * 8 + 4) = o1;
  }
}

// ---------------------------------------------------------------------------
// Kernel 2: recurrence via MFMA (r6 structure + pipelining).
// One 512-thread WG (8 waves) per batch row. Wave w owns rows 64w..64w+63 as
// 4 row-tiles of mfma_f32_16x16x32_f16:
//   tiles 0,1: AGPR-resident (af[2][16] = 128 regs)
//   tile  2:   LDS-resident, read via 2-deep lfA/lfB ping-pong (each
//              ds_read_b128 issued one kt-phase before its MFMA; the kt=15
//              refill primes NEXT step across the barrier — LDS W immutable)
//   tile  3:   streamed from L2: sf[16] regs loaded at the END of the
//              previous step (pre-barrier issue, lgkm-only barrier doesn't
//              drain vmcnt) -> ~600 cyc load-to-use, L2 latency hidden.
// h: fp16[2][512] dbuf in LDS; B-frags are 16-way broadcast b128 reads.
// All 16 MFMA columns equal -> uniform 16->1 static select epilogue.
// ---------------------------------------------------------------------------
__global__ __attribute__((amdgpu_flat_work_group_size(512, 512),
                          amdgpu_waves_per_eu(2, 2)))
void rnn_kernel(const float* __restrict__ w_hh, const uint4* __restrict__ wsf,
                float* __restrict__ out) {
  extern __shared__ char smem[];
  uint4* lds_w = (uint4*)smem;                    // [8][16][64] frags (128 KB)
  _Float16* lds_h = (_Float16*)(smem + 131072);   // 2 x 512

  const int b = blockIdx.x;
  const int tid = threadIdx.x;
  const int w = tid >> 6;
  const int lane = tid & 63;
  const int m = lane & 15;   // A row within tile / C col
  const int g = lane >> 4;   // k-group / C row-group

  // --- AGPR tiles 0,1: rows 64w + tile*16 + m ---
  f16x8 af[2][16];
#pragma unroll
  for (int tile = 0; tile < 2; ++tile) {
    const float* rowp = w_hh + (size_t)(64 * w + tile * 16 + m) * H_SZ;
#pragma unroll
    for (int kt = 0; kt < 16; ++kt)
      af[tile][kt] = pack8(rowp + kt * 32 + g * 8);
  }
  // --- LDS tile 2: rows 64w + 32 + m; each lane writes its own fragment ---
  {
    const float* rowp = w_hh + (size_t)(64 * w + 32 + m) * H_SZ;
#pragma unroll
    for (int kt = 0; kt < 16; ++kt) {
      f16x8 a = pack8(rowp + kt * 32 + g * 8);
      lds_w[(w * 16 + kt) * 64 + lane] = __builtin_bit_cast(uint4, a);
    }
  }
  // h0 = 0, both buffers
  lds_h[tid] = (_Float16)0.f;
  lds_h[512 + tid] = (_Float16)0.f;
  __syncthreads();

  // this lane's output row (bijective within the block)
  const int row = 64 * w + (m >> 2) * 16 + g * 4 + (m & 3);
  const bool b8 = (m & 8) != 0, b4 = (m & 4) != 0;
  const bool b2 = (m & 2) != 0, b1 = (m & 1) != 0;

  const uint4* swp = wsf + (size_t)(w * 16) * 64 + lane;    // stream frags
  const uint4* lwp = lds_w + (w * 16) * 64 + lane;          // LDS frags

  float* outb = out + (size_t)b * T_SZ * H_SZ;
  float xc = outb[row];  // xp for t=0
  float hlast = 0.f;

  // prime: stream frags for t=0 and first LDS frag
  uint4 sf[16];
#pragma unroll
  for (int k = 0; k < 16; ++k) sf[k] = swp[k * 64];
  uint4 lfA = lwp[0], lfB;

#pragma unroll 1
  for (int t = 0; t < T_SZ; ++t) {
    const _Float16* hb = lds_h + (t & 1) * 512;
    f32x4 c0 = {0.f, 0.f, 0.f, 0.f}, c1 = c0, c2 = c0, c3 = c0;

    // kt phases: lfA/lfB ping-pong (use one, load the other one kt ahead);
    // sf[] were loaded pre-barrier last step. kt=15's refill (lfA=lwp[0])
    // primes the NEXT step.
#define STEP_E(kt)                                                            \
    {                                                                         \
      f16x8 bf = *(const f16x8*)(hb + (kt) * 32 + g * 8);                     \
      lfB = lwp[((kt) + 1) * 64];                                             \
      c0 = __builtin_amdgcn_mfma_f32_16x16x32_f16(af[0][kt], bf, c0, 0, 0, 0);\
      c1 = __builtin_amdgcn_mfma_f32_16x16x32_f16(af[1][kt], bf, c1, 0, 0, 0);\
      c2 = __builtin_amdgcn_mfma_f32_16x16x32_f16(                            \
          __builtin_bit_cast(f16x8, lfA), bf, c2, 0, 0, 0);                   \
      c3 = __builtin_amdgcn_mfma_f32_16x16x32_f16(                            \
          __builtin_bit_cast(f16x8, sf[kt]), bf, c3, 0, 0, 0);                \
    }
#define STEP_O(kt, NXT)                                                       \
    {                                                                         \
      f16x8 bf = *(const f16x8*)(hb + (kt) * 32 + g * 8);                     \
      lfA = lwp[(NXT) * 64];                                                  \
      c0 = __builtin_amdgcn_mfma_f32_16x16x32_f16(af[0][kt], bf, c0, 0, 0, 0);\
      c1 = __builtin_amdgcn_mfma_f32_16x16x32_f16(af[1][kt], bf, c1, 0, 0, 0);\
      c2 = __builtin_amdgcn_mfma_f32_16x16x32_f16(                            \
          __builtin_bit_cast(f16x8, lfB), bf, c2, 0, 0, 0);                   \
      c3 = __builtin_amdgcn_mfma_f32_16x16x32_f16(                            \
          __builtin_bit_cast(f16x8, sf[kt]), bf, c3, 0, 0, 0);                \
    }
    STEP_E(0)  STEP_O(1, 2)   STEP_E(2)  STEP_O(3, 4)
    STEP_E(4)  STEP_O(5, 6)   STEP_E(6)  STEP_O(7, 8)
    STEP_E(8)  STEP_O(9, 10)  STEP_E(10) STEP_O(11, 12)
    STEP_E(12) STEP_O(13, 14) STEP_E(14) STEP_O(15, 0)
#undef STEP_E
#undef STEP_O

    // issue NEXT step's stream loads now (pre-barrier; vmcnt not drained by
    // the barrier -> they land during next step's MFMA phase)
#pragma unroll
    for (int k = 0; k < 16; ++k) sf[k] = swp[k * 64];
    // prefetch next xp
    int tn = (t + 1 < T_SZ) ? t + 1 : t;
    float xn = outb[(size_t)tn * H_SZ + row];

    // static 16->1 select: tile = m>>2 (bits b8,b4), reg = m&3 (bits b2,b1)
    float p0 = b8 ? (b4 ? c3[0] : c2[0]) : (b4 ? c1[0] : c0[0]);
    float p1 = b8 ? (b4 ? c3[1] : c2[1]) : (b4 ? c1[1] : c0[1]);
    float p2 = b8 ? (b4 ? c3[2] : c2[2]) : (b4 ? c1[2] : c0[2]);
    float p3 = b8 ? (b4 ? c3[3] : c2[3]) : (b4 ? c1[3] : c0[3]);
    float q01 = b1 ? p1 : p0;
    float q23 = b1 ? p3 : p2;
    float v = b2 ? q23 : q01;

    float hnew = fast_tanh(xc + v);
    outb[(size_t)t * H_SZ + row] = hnew;                 // floats past barrier
    lds_h[((t + 1) & 1) * 512 + row] = (_Float16)hnew;   // drained by barrier
    hlast = hnew;
    xc = xn;
    step_barrier();
  }

  // hidden = h_{T-1}
  out[(size_t)B_SZ * T_SZ * H_SZ + (size_t)b * H_SZ + row] = hlast;
}

extern "C" void kernel_launch(void* const* d_in, const int* in_sizes, int n_in,
                              void* d_out, int out_size, void* d_ws,
                              size_t ws_size, hipStream_t stream) {
  (void)in_sizes; (void)n_in; (void)out_size; (void)ws_size;
  const float* q    = (const float*)d_in[0];
  const float* w_ih = (const float*)d_in[1];
  const float* w_hh = (const float*)d_in[2];
  const float* b_ih = (const float*)d_in[3];
  const float* b_hh = (const float*)d_in[4];
  float* out = (float*)d_out;
  uint4* wsf = (uint4*)d_ws;   // 8192 frags x 16 B = 128 KB of scratch

  prep_kernel<<<dim3(16), dim3(512), 0, stream>>>(w_hh, wsf);

  proj_kernel<<<dim3((B_SZ * T_SZ / 128) * (H_SZ / 128)), dim3(256), 0,
                stream>>>(q, w_ih, b_ih, b_hh, out);

  // 131072 (LDS W tile) + 2048 (h dbuf) = 133120 B dynamic LDS (>64 KB opt-in)
  hipFuncSetAttribute(reinterpret_cast<const void*>(rnn_kernel),
                      hipFuncAttributeMaxDynamicSharedMemorySize, 133120);
  rnn_kernel<<<dim3(B_SZ), dim3(512), 133120, stream>>>(w_hh, wsf, out);
}